// Round 2
// baseline (1568.941 us; speedup 1.0000x reference)
//
#include <hip/hip_runtime.h>

// Problem constants
#define NB    64      // batch
#define LCAP  51      // caption length
#define TT    50      // decode steps
#define HID   512
#define EMB   512
#define VOC   30000
#define ENCD  2048
#define G4    2048    // 4*HID

typedef unsigned short u16;
typedef __attribute__((ext_vector_type(8))) short bf16x8;
typedef __attribute__((ext_vector_type(4))) float f32x4;

__device__ __forceinline__ u16 f2bf(float x) {
  union { float f; unsigned u; } v; v.f = x;
  unsigned r = v.u + 0x7fffu + ((v.u >> 16) & 1u);
  return (u16)(r >> 16);
}

// ---------------- sort + int outputs + row compaction + barrier-flag init ----------------
__global__ __launch_bounds__(256) void sort_k(const int* __restrict__ cap_len,
                                              const int* __restrict__ caps,
                                              float* __restrict__ out,
                                              int* __restrict__ sind,
                                              int* __restrict__ dlen,
                                              int* __restrict__ rowmap,
                                              int* __restrict__ zmap,
                                              int* __restrict__ nact,
                                              int* __restrict__ flags) {
  __shared__ int smlen[NB];
  __shared__ int smpos[NB];
  __shared__ int sdl[NB];
  __shared__ int off[NB];
  __shared__ int zoff[NB];
  int tid = threadIdx.x;
  if (tid < NB) { smlen[tid] = cap_len[tid]; flags[tid] = 0; }
  __syncthreads();
  if (tid < NB) {
    int li = smlen[tid];
    int rank = 0;
    for (int j = 0; j < NB; ++j) {
      int lj = smlen[j];
      rank += (lj > li || (lj == li && j < tid)) ? 1 : 0;
    }
    smpos[rank] = tid;
  }
  __syncthreads();
  if (tid < NB) {
    int src = smpos[tid];
    int dl = smlen[src] - 1;
    sind[tid] = src;
    dlen[tid] = dl;
    sdl[tid] = dl;
    float* caps_out = out + (size_t)NB * TT * VOC;          // 96,000,000
    for (int l = 0; l < LCAP; ++l)
      caps_out[tid * LCAP + l] = (float)caps[src * LCAP + l];
    out[96003264 + tid] = (float)dl;       // dec_len
    out[96003328 + tid] = (float)src;      // sort_ind
  }
  __syncthreads();
  if (tid == 0) {
    int s = 0, z = 0;
    for (int b = 0; b < NB; ++b) {
      off[b] = s;  s += sdl[b];
      zoff[b] = z; z += TT - sdl[b];
    }
    *nact = s;
  }
  __syncthreads();
  for (int m = tid; m < NB * TT; m += 256) {
    int b = (m * 5243) >> 18;     // m/50 for m<43690
    int t = m - b * TT;
    if (t < sdl[b]) rowmap[off[b] + t] = m;
    else            zmap[zoff[b] + (t - sdl[b])] = m;
  }
}

// ---------------- converts / gathers ----------------
__global__ __launch_bounds__(256) void conv4(const float* __restrict__ src,
                                             u16* __restrict__ dst, int n4) {
  int i = blockIdx.x * 256 + threadIdx.x;
  if (i >= n4) return;
  float4 v = ((const float4*)src)[i];
  ushort4 o;
  o.x = f2bf(v.x); o.y = f2bf(v.y); o.z = f2bf(v.z); o.w = f2bf(v.w);
  ((ushort4*)dst)[i] = o;
}

// Winit = concat(w_init_h, w_init_c) rows -> [1024][2048] bf16
__global__ __launch_bounds__(256) void conv_winit_k(const float* __restrict__ wh,
                                                    const float* __restrict__ wc,
                                                    u16* __restrict__ dst) {
  int i = blockIdx.x * 256 + threadIdx.x;   // i over 2097152/4
  if (i >= 524288) return;
  int e = i * 4;
  int row = e >> 11;           // /2048
  int col = e & 2047;
  const float* src = (row < 512) ? (wh + (size_t)row * 2048 + col)
                                 : (wc + (size_t)(row - 512) * 2048 + col);
  float4 v = *(const float4*)src;
  ushort4 o;
  o.x = f2bf(v.x); o.y = f2bf(v.y); o.z = f2bf(v.z); o.w = f2bf(v.w);
  ((ushort4*)dst)[i] = o;
}

// enc_bf[r][k] = bf16(encoder_out[sind[r]][k])
__global__ __launch_bounds__(256) void gather_enc_k(const float* __restrict__ enc,
                                                    const int* __restrict__ sind,
                                                    u16* __restrict__ dst) {
  int i = blockIdx.x * 256 + threadIdx.x;   // over 64*2048/4
  if (i >= 32768) return;
  int e = i * 4;
  int r = e >> 11;
  int k = e & 2047;
  float4 v = *(const float4*)(enc + (size_t)sind[r] * ENCD + k);
  ushort4 o;
  o.x = f2bf(v.x); o.y = f2bf(v.y); o.z = f2bf(v.z); o.w = f2bf(v.w);
  ((ushort4*)dst)[i] = o;
}

// Xb[(b*50+t)][k] = bf16(emb[caps[sind[b]*51 + t]][k])
__global__ __launch_bounds__(256) void gather_x_k(const float* __restrict__ emb,
                                                  const int* __restrict__ caps,
                                                  const int* __restrict__ sind,
                                                  u16* __restrict__ dst) {
  int i = blockIdx.x * 256 + threadIdx.x;   // over 3200*512/4
  if (i >= 409600) return;
  int e = i * 4;
  int m = e >> 9;              // /512
  int k = e & 511;
  unsigned b = ((unsigned)m * 5243u) >> 18;   // m/50
  int t = m - (int)b * TT;
  int cap = caps[sind[b] * LCAP + t];
  float4 v = *(const float4*)(emb + (size_t)cap * EMB + k);
  ushort4 o;
  o.x = f2bf(v.x); o.y = f2bf(v.y); o.z = f2bf(v.z); o.w = f2bf(v.w);
  ((ushort4*)dst)[i] = o;
}

// ---------------- bf16 MFMA GEMM: C[M][N] = A[M][K] * B[N][K]^T ----------------
// grid: x = m-blocks (consecutive blocks share a weight panel), y = n-blocks.
// EPI 0: xW   -> out[row*Nr+col] = acc + bias0[col] + bias1[col]
// EPI 1: init -> col<512: h0 bf16 into outv; else c0 fp32 into out1
// EPI 2: fc   -> compacted rows via rowmap; masked rows zero-filled in slices
#define BM 128
#define BN 128
#define BK 32
#define LDT 40    // LDS row stride (bf16 elems); 2-way max bank aliasing

template <int EPI>
__global__ __launch_bounds__(256) void gemm_bt(const u16* __restrict__ A,
                                               const u16* __restrict__ Bm,
                                               int Mr, int Nr, int K,
                                               void* __restrict__ outv,
                                               float* __restrict__ out1,
                                               const float* __restrict__ bias0,
                                               const float* __restrict__ bias1,
                                               const int* __restrict__ rowmap,
                                               const int* __restrict__ zmap,
                                               const int* __restrict__ nactp) {
  __shared__ u16 As[BM * LDT];
  __shared__ u16 Bs[BN * LDT];
  __shared__ int rmap_s[BM];
  int tid = threadIdx.x;
  int mBase = blockIdx.x * BM;
  int nBase = blockIdx.y * BN;
  int nact = Mr;

  if (EPI == 2) {
    nact = nactp[0];
    int nz = Mr - nact;
    // zero-fill duty: every block zeroes its column slice for rows r = x (mod gridDim.x)
    if (tid < 32 && nz > 0) {
      int nc4 = min(BN, Nr - nBase) >> 2;   // float4 per slice (<=32)
      float4 zz = {0.f, 0.f, 0.f, 0.f};
      if (tid < nc4) {
        for (int r = blockIdx.x; r < nz; r += gridDim.x) {
          float4* dst = (float4*)((float*)outv + (size_t)zmap[r] * Nr + nBase);
          dst[tid] = zz;
        }
      }
    }
    int na = (nact + BM - 1) >> 7;          // active m-blocks
    if ((int)blockIdx.x >= na) return;
    if (tid < BM) {
      int idx = mBase + tid;
      rmap_s[tid] = (idx < nact) ? rowmap[idx] : rowmap[nact - 1];
    }
    __syncthreads();
  }

  int wid = tid >> 6, lane = tid & 63;
  int wm = (wid >> 1) * 64, wn = (wid & 1) * 64;
  int lm = lane & 15, lq = lane >> 4;

  f32x4 acc[4][4];
  for (int i = 0; i < 4; ++i)
    for (int j = 0; j < 4; ++j)
      acc[i][j] = (f32x4){0.f, 0.f, 0.f, 0.f};

  int nkt = K / BK;
  for (int kt = 0; kt < nkt; ++kt) {
    for (int it = 0; it < 2; ++it) {
      int li = tid + it * 256;       // 0..511
      int row = li >> 2, kq = li & 3;
      {
        int gr = (EPI == 2) ? rmap_s[row] : min(mBase + row, Mr - 1);
        uint4 v = *(const uint4*)(A + (size_t)gr * K + kt * BK + kq * 8);
        *(uint4*)&As[row * LDT + kq * 8] = v;
      }
      {
        int gr = min(nBase + row, Nr - 1);
        uint4 v = *(const uint4*)(Bm + (size_t)gr * K + kt * BK + kq * 8);
        *(uint4*)&Bs[row * LDT + kq * 8] = v;
      }
    }
    __syncthreads();
    bf16x8 af[4], bfr[4];
    for (int i = 0; i < 4; ++i)
      af[i] = *(const bf16x8*)&As[(wm + i * 16 + lm) * LDT + lq * 8];
    for (int j = 0; j < 4; ++j)
      bfr[j] = *(const bf16x8*)&Bs[(wn + j * 16 + lm) * LDT + lq * 8];
    for (int i = 0; i < 4; ++i)
      for (int j = 0; j < 4; ++j)
        acc[i][j] = __builtin_amdgcn_mfma_f32_16x16x32_bf16(af[i], bfr[j], acc[i][j], 0, 0, 0);
    __syncthreads();
  }

  // epilogue: C row = (lane>>4)*4 + reg, col = lane&15
  for (int i = 0; i < 4; ++i) {
    int rloc0 = wm + i * 16 + (lane >> 4) * 4;
    for (int j = 0; j < 4; ++j) {
      int col = nBase + wn + j * 16 + (lane & 15);
      for (int r = 0; r < 4; ++r) {
        int rloc = rloc0 + r;
        float v = acc[i][j][r];
        if (EPI == 0) {
          int row = mBase + rloc;
          if (row < Mr && col < Nr)
            ((float*)outv)[(size_t)row * Nr + col] = v + bias0[col] + bias1[col];
        } else if (EPI == 1) {
          int row = mBase + rloc;
          if (row < Mr && col < Nr) {
            if (col < 512) ((u16*)outv)[(size_t)row * 512 + col] = f2bf(v + bias0[col]);
            else           out1[(size_t)row * 512 + (col - 512)] = v + bias1[col - 512];
          }
        } else {
          if (col < Nr && mBase + rloc < nact)
            ((float*)outv)[(size_t)rmap_s[rloc] * Nr + col] = v + bias0[col];
        }
      }
    }
  }
}

// ---------------- persistent LSTM: all 50 steps in one launch ----------------
// 64 blocks x 256 threads (1 block/CU, guaranteed co-resident).
// Block j owns units u0=j*8..j*8+7 (32 gate columns). w_hh bf16 B-fragments
// live in registers across all steps. h ping-pongs in global as bf16; c in regs.
// One software grid-barrier per step (per-block flag + 64-lane poll).
__global__ __launch_bounds__(256, 1) void lstm_seq(const float* __restrict__ w_hh,
                                                   const float* __restrict__ xW,
                                                   const float* __restrict__ cbuf,
                                                   u16* __restrict__ hbuf,
                                                   u16* __restrict__ Hs,
                                                   int* __restrict__ flags) {
  __shared__ u16 wsm[32 * 520];
  __shared__ float gsm[64][36];
  int tid = threadIdx.x;
  int j = blockIdx.x;
  int u0 = j * 8;

  // stage w_hh chunk (rows g*512+u0+ul for g=0..3, ul=0..7) -> wsm[g*8+ul][0..511]
  {
    int r = tid >> 3;              // 0..31
    int cc = (tid & 7) * 64;       // 64 floats per thread
    const float* src = w_hh + (size_t)((r >> 3) * HID + u0 + (r & 7)) * HID + cc;
    u16* dst = &wsm[r * 520 + cc];
#pragma unroll
    for (int q = 0; q < 16; ++q) {
      float4 v = ((const float4*)src)[q];
      ushort4 o; o.x = f2bf(v.x); o.y = f2bf(v.y); o.z = f2bf(v.z); o.w = f2bf(v.w);
      ((ushort4*)dst)[q] = o;
    }
  }
  __syncthreads();

  int wave = tid >> 6, lane = tid & 63;
  int lm = lane & 15, lq = lane >> 4;

  // time-invariant B fragments -> registers (2 n-tiles x 16 k-chunks)
  bf16x8 bfrag[2][16];
#pragma unroll
  for (int n = 0; n < 2; ++n)
#pragma unroll
    for (int kq = 0; kq < 16; ++kq)
      bfrag[n][kq] = *(const bf16x8*)&wsm[(n * 16 + lm) * 520 + kq * 32 + lq * 8];

  // c-state in registers: cells (b0,ul) and (b1,ul)
  int b0 = tid >> 3, ul = tid & 7;
  int b1 = b0 + 32;
  float creg0 = cbuf[(size_t)b0 * HID + u0 + ul];
  float creg1 = cbuf[(size_t)b1 * HID + u0 + ul];

  const int arow = (wave * 16 + lm) * HID;

  for (int t = 0; t < TT; ++t) {
    const u16* hcur = hbuf + (size_t)(t & 1) * (NB * HID);
    u16* hnxt = hbuf + (size_t)((t + 1) & 1) * (NB * HID);

    // prefetch xW gate terms for pointwise
    float xg0[4], xg1[4];
    {
      const float* xw0 = xW + (size_t)(b0 * TT + t) * G4 + u0 + ul;
      const float* xw1 = xW + (size_t)(b1 * TT + t) * G4 + u0 + ul;
#pragma unroll
      for (int g = 0; g < 4; ++g) { xg0[g] = xw0[g * HID]; xg1[g] = xw1[g * HID]; }
    }

    // A fragments straight from global (h is L2-resident, each byte read once/block)
    bf16x8 afr[16];
#pragma unroll
    for (int kq = 0; kq < 16; ++kq)
      afr[kq] = *(const bf16x8*)(hcur + arow + kq * 32 + lq * 8);

    f32x4 acc0 = (f32x4){0.f, 0.f, 0.f, 0.f};
    f32x4 acc1 = (f32x4){0.f, 0.f, 0.f, 0.f};
#pragma unroll
    for (int kq = 0; kq < 16; ++kq) {
      acc0 = __builtin_amdgcn_mfma_f32_16x16x32_bf16(afr[kq], bfrag[0][kq], acc0, 0, 0, 0);
      acc1 = __builtin_amdgcn_mfma_f32_16x16x32_bf16(afr[kq], bfrag[1][kq], acc1, 0, 0, 0);
    }
#pragma unroll
    for (int r = 0; r < 4; ++r) {
      gsm[wave * 16 + lq * 4 + r][lm]      = acc0[r];
      gsm[wave * 16 + lq * 4 + r][16 + lm] = acc1[r];
    }
    __syncthreads();

    // pointwise: 2 cells per thread
    {
      float gi = gsm[b0][ul]      + xg0[0];
      float gf = gsm[b0][8 + ul]  + xg0[1];
      float gg = gsm[b0][16 + ul] + xg0[2];
      float go = gsm[b0][24 + ul] + xg0[3];
      float si = 1.f / (1.f + __expf(-gi));
      float sf = 1.f / (1.f + __expf(-gf));
      float so = 1.f / (1.f + __expf(-go));
      float tg = tanhf(gg);
      float cn = sf * creg0 + si * tg;
      creg0 = cn;
      float hn = so * tanhf(cn);
      u16 hb = f2bf(hn);
      hnxt[(size_t)b0 * HID + u0 + ul] = hb;
      Hs[(size_t)(b0 * TT + t) * HID + u0 + ul] = hb;
    }
    {
      float gi = gsm[b1][ul]      + xg1[0];
      float gf = gsm[b1][8 + ul]  + xg1[1];
      float gg = gsm[b1][16 + ul] + xg1[2];
      float go = gsm[b1][24 + ul] + xg1[3];
      float si = 1.f / (1.f + __expf(-gi));
      float sf = 1.f / (1.f + __expf(-gf));
      float so = 1.f / (1.f + __expf(-go));
      float tg = tanhf(gg);
      float cn = sf * creg1 + si * tg;
      creg1 = cn;
      float hn = so * tanhf(cn);
      u16 hb = f2bf(hn);
      hnxt[(size_t)b1 * HID + u0 + ul] = hb;
      Hs[(size_t)(b1 * TT + t) * HID + u0 + ul] = hb;
    }

    // grid barrier: release own flag, poll all 64
    __threadfence();
    __syncthreads();
    if (tid == 0)
      __hip_atomic_store(&flags[j], t + 1, __ATOMIC_RELEASE, __HIP_MEMORY_SCOPE_AGENT);
    if (tid < 64) {
      while (__hip_atomic_load(&flags[tid], __ATOMIC_ACQUIRE, __HIP_MEMORY_SCOPE_AGENT) < t + 1)
        __builtin_amdgcn_s_sleep(2);
    }
    __syncthreads();
    __threadfence();
  }
}

// ---------------- launcher ----------------
extern "C" void kernel_launch(void* const* d_in, const int* in_sizes, int n_in,
                              void* d_out, int out_size, void* d_ws, size_t ws_size,
                              hipStream_t stream) {
  const float* encoder_out = (const float*)d_in[0];
  const int*   caps        = (const int*)d_in[1];
  const int*   cap_len     = (const int*)d_in[2];
  const float* emb         = (const float*)d_in[3];
  const float* w_ih        = (const float*)d_in[4];
  const float* b_ih        = (const float*)d_in[5];
  const float* w_hh        = (const float*)d_in[6];
  const float* b_hh        = (const float*)d_in[7];
  const float* w_init_h    = (const float*)d_in[8];
  const float* b_init_h    = (const float*)d_in[9];
  const float* w_init_c    = (const float*)d_in[10];
  const float* b_init_c    = (const float*)d_in[11];
  const float* w_fc        = (const float*)d_in[12];
  const float* b_fc        = (const float*)d_in[13];
  float* out = (float*)d_out;

  char* ws = (char*)d_ws;
  int*   sind   = (int*)(ws + 0);          // 256 B
  int*   dlen   = (int*)(ws + 256);        // 256 B
  int*   nact   = (int*)(ws + 512);        // 64 B
  int*   flags  = (int*)(ws + 576);        // 256 B
  int*   rowmap = (int*)(ws + 832);        // 12800 B
  int*   zmap   = (int*)(ws + 13632);      // 12800 B
  float* cbuf   = (float*)(ws + 26496);    // 64*512*4 = 131072
  u16*   hbuf   = (u16*)(ws + 157568);     // 2*64*512*2 = 131072
  float* xW     = (float*)(ws + 288640);   // 3200*2048*4 = 26214400
  u16*   Hs     = (u16*)(ws + 26503040);   // 3200*512*2 = 3276800
  u16*   Xb     = (u16*)(ws + 29779840);   // 3276800
  u16*   Wih    = (u16*)(ws + 33056640);   // 2097152
  u16*   Winit  = (u16*)(ws + 35153792);   // 4194304
  u16*   Wfc    = (u16*)(ws + 39348096);   // 30720000
  u16*   Ebf    = (u16*)(ws + 70068096);   // 262144  -> end 70330240

  sort_k<<<1, 256, 0, stream>>>(cap_len, caps, out, sind, dlen, rowmap, zmap, nact, flags);
  conv4<<<1024, 256, 0, stream>>>(w_ih, Wih, 262144);
  conv_winit_k<<<2048, 256, 0, stream>>>(w_init_h, w_init_c, Winit);
  conv4<<<15000, 256, 0, stream>>>(w_fc, Wfc, 3840000);
  gather_enc_k<<<128, 256, 0, stream>>>(encoder_out, sind, Ebf);
  gather_x_k<<<1600, 256, 0, stream>>>(emb, caps, sind, Xb);

  // h0 (bf16) | c0 (fp32)
  gemm_bt<1><<<dim3(1, 8), 256, 0, stream>>>(Ebf, Winit, 64, 1024, 2048,
                                             hbuf, cbuf, b_init_h, b_init_c,
                                             nullptr, nullptr, nullptr);
  // xW = X @ w_ih^T + b_ih + b_hh  (all steps at once)
  gemm_bt<0><<<dim3(25, 16), 256, 0, stream>>>(Xb, Wih, 3200, 2048, 512,
                                               xW, nullptr, b_ih, b_hh,
                                               nullptr, nullptr, nullptr);
  // all 50 LSTM steps, one launch
  lstm_seq<<<64, 256, 0, stream>>>(w_hh, xW, cbuf, hbuf, Hs, flags);
  // predictions = Hs @ w_fc^T + b_fc (compacted rows; masked rows zero-filled)
  gemm_bt<2><<<dim3(25, 235), 256, 0, stream>>>(Hs, Wfc, 3200, VOC, 512,
                                                out, nullptr, b_fc, nullptr,
                                                rowmap, zmap, nact);
}

// Round 3
// 1189.371 us; speedup vs baseline: 1.3191x; 1.3191x over previous
//
#include <hip/hip_runtime.h>

// Problem constants
#define NB    64      // batch
#define LCAP  51      // caption length
#define TT    50      // decode steps
#define HID   512
#define EMB   512
#define VOC   30000
#define ENCD  2048
#define G4    2048    // 4*HID

typedef unsigned short u16;
typedef unsigned int   u32;
typedef __attribute__((ext_vector_type(8))) short bf16x8;
typedef __attribute__((ext_vector_type(4))) float f32x4;

__device__ __forceinline__ u16 f2bf(float x) {
  union { float f; unsigned u; } v; v.f = x;
  unsigned r = v.u + 0x7fffu + ((v.u >> 16) & 1u);
  return (u16)(r >> 16);
}

// ---------------- sort + int outputs + row compaction + barrier-flag init ----------------
__global__ __launch_bounds__(256) void sort_k(const int* __restrict__ cap_len,
                                              const int* __restrict__ caps,
                                              float* __restrict__ out,
                                              int* __restrict__ sind,
                                              int* __restrict__ dlen,
                                              int* __restrict__ rowmap,
                                              int* __restrict__ zmap,
                                              int* __restrict__ nact,
                                              int* __restrict__ flags) {
  __shared__ int smlen[NB];
  __shared__ int smpos[NB];
  __shared__ int sdl[NB];
  __shared__ int off[NB];
  __shared__ int zoff[NB];
  int tid = threadIdx.x;
  if (tid < NB) { smlen[tid] = cap_len[tid]; flags[tid] = 0; }
  __syncthreads();
  if (tid < NB) {
    int li = smlen[tid];
    int rank = 0;
    for (int j = 0; j < NB; ++j) {
      int lj = smlen[j];
      rank += (lj > li || (lj == li && j < tid)) ? 1 : 0;
    }
    smpos[rank] = tid;
  }
  __syncthreads();
  if (tid < NB) {
    int src = smpos[tid];
    int dl = smlen[src] - 1;
    sind[tid] = src;
    dlen[tid] = dl;
    sdl[tid] = dl;
    float* caps_out = out + (size_t)NB * TT * VOC;          // 96,000,000
    for (int l = 0; l < LCAP; ++l)
      caps_out[tid * LCAP + l] = (float)caps[src * LCAP + l];
    out[96003264 + tid] = (float)dl;       // dec_len
    out[96003328 + tid] = (float)src;      // sort_ind
  }
  __syncthreads();
  if (tid == 0) {
    int s = 0, z = 0;
    for (int b = 0; b < NB; ++b) {
      off[b] = s;  s += sdl[b];
      zoff[b] = z; z += TT - sdl[b];
    }
    *nact = s;
  }
  __syncthreads();
  for (int m = tid; m < NB * TT; m += 256) {
    int b = (m * 5243) >> 18;     // m/50 for m<43690
    int t = m - b * TT;
    if (t < sdl[b]) rowmap[off[b] + t] = m;
    else            zmap[zoff[b] + (t - sdl[b])] = m;
  }
}

// ---------------- converts / gathers ----------------
__global__ __launch_bounds__(256) void conv4(const float* __restrict__ src,
                                             u16* __restrict__ dst, int n4) {
  int i = blockIdx.x * 256 + threadIdx.x;
  if (i >= n4) return;
  float4 v = ((const float4*)src)[i];
  ushort4 o;
  o.x = f2bf(v.x); o.y = f2bf(v.y); o.z = f2bf(v.z); o.w = f2bf(v.w);
  ((ushort4*)dst)[i] = o;
}

// Winit = concat(w_init_h, w_init_c) rows -> [1024][2048] bf16
__global__ __launch_bounds__(256) void conv_winit_k(const float* __restrict__ wh,
                                                    const float* __restrict__ wc,
                                                    u16* __restrict__ dst) {
  int i = blockIdx.x * 256 + threadIdx.x;   // i over 2097152/4
  if (i >= 524288) return;
  int e = i * 4;
  int row = e >> 11;           // /2048
  int col = e & 2047;
  const float* src = (row < 512) ? (wh + (size_t)row * 2048 + col)
                                 : (wc + (size_t)(row - 512) * 2048 + col);
  float4 v = *(const float4*)src;
  ushort4 o;
  o.x = f2bf(v.x); o.y = f2bf(v.y); o.z = f2bf(v.z); o.w = f2bf(v.w);
  ((ushort4*)dst)[i] = o;
}

// enc_bf[r][k] = bf16(encoder_out[sind[r]][k])
__global__ __launch_bounds__(256) void gather_enc_k(const float* __restrict__ enc,
                                                    const int* __restrict__ sind,
                                                    u16* __restrict__ dst) {
  int i = blockIdx.x * 256 + threadIdx.x;   // over 64*2048/4
  if (i >= 32768) return;
  int e = i * 4;
  int r = e >> 11;
  int k = e & 2047;
  float4 v = *(const float4*)(enc + (size_t)sind[r] * ENCD + k);
  ushort4 o;
  o.x = f2bf(v.x); o.y = f2bf(v.y); o.z = f2bf(v.z); o.w = f2bf(v.w);
  ((ushort4*)dst)[i] = o;
}

// Xb[(b*50+t)][k] = bf16(emb[caps[sind[b]*51 + t]][k])
__global__ __launch_bounds__(256) void gather_x_k(const float* __restrict__ emb,
                                                  const int* __restrict__ caps,
                                                  const int* __restrict__ sind,
                                                  u16* __restrict__ dst) {
  int i = blockIdx.x * 256 + threadIdx.x;   // over 3200*512/4
  if (i >= 409600) return;
  int e = i * 4;
  int m = e >> 9;              // /512
  int k = e & 511;
  unsigned b = ((unsigned)m * 5243u) >> 18;   // m/50
  int t = m - (int)b * TT;
  int cap = caps[sind[b] * LCAP + t];
  float4 v = *(const float4*)(emb + (size_t)cap * EMB + k);
  ushort4 o;
  o.x = f2bf(v.x); o.y = f2bf(v.y); o.z = f2bf(v.z); o.w = f2bf(v.w);
  ((ushort4*)dst)[i] = o;
}

// ---------------- bf16 MFMA GEMM: C[M][N] = A[M][K] * B[N][K]^T ----------------
// grid: x = m-blocks (consecutive blocks share a weight panel), y = n-blocks.
// EPI 0: xW   -> out[row*Nr+col] = acc + bias0[col] + bias1[col]
// EPI 1: init -> col<512: h0 bf16 into outv; else c0 fp32 into out1
// EPI 2: fc   -> compacted rows via rowmap; masked rows zero-filled in slices
#define BM 128
#define BN 128
#define BK 32
#define LDT 40    // LDS row stride (bf16 elems); 2-way max bank aliasing

template <int EPI>
__global__ __launch_bounds__(256) void gemm_bt(const u16* __restrict__ A,
                                               const u16* __restrict__ Bm,
                                               int Mr, int Nr, int K,
                                               void* __restrict__ outv,
                                               float* __restrict__ out1,
                                               const float* __restrict__ bias0,
                                               const float* __restrict__ bias1,
                                               const int* __restrict__ rowmap,
                                               const int* __restrict__ zmap,
                                               const int* __restrict__ nactp) {
  __shared__ u16 As[BM * LDT];
  __shared__ u16 Bs[BN * LDT];
  __shared__ int rmap_s[BM];
  int tid = threadIdx.x;
  int mBase = blockIdx.x * BM;
  int nBase = blockIdx.y * BN;
  int nact = Mr;

  if (EPI == 2) {
    nact = nactp[0];
    int nz = Mr - nact;
    // zero-fill duty: every block zeroes its column slice for rows r = x (mod gridDim.x)
    if (tid < 32 && nz > 0) {
      int nc4 = min(BN, Nr - nBase) >> 2;   // float4 per slice (<=32)
      float4 zz = {0.f, 0.f, 0.f, 0.f};
      if (tid < nc4) {
        for (int r = blockIdx.x; r < nz; r += gridDim.x) {
          float4* dst = (float4*)((float*)outv + (size_t)zmap[r] * Nr + nBase);
          dst[tid] = zz;
        }
      }
    }
    int na = (nact + BM - 1) >> 7;          // active m-blocks
    if ((int)blockIdx.x >= na) return;
    if (tid < BM) {
      int idx = mBase + tid;
      rmap_s[tid] = (idx < nact) ? rowmap[idx] : rowmap[nact - 1];
    }
    __syncthreads();
  }

  int wid = tid >> 6, lane = tid & 63;
  int wm = (wid >> 1) * 64, wn = (wid & 1) * 64;
  int lm = lane & 15, lq = lane >> 4;

  f32x4 acc[4][4];
  for (int i = 0; i < 4; ++i)
    for (int j = 0; j < 4; ++j)
      acc[i][j] = (f32x4){0.f, 0.f, 0.f, 0.f};

  int nkt = K / BK;
  for (int kt = 0; kt < nkt; ++kt) {
    for (int it = 0; it < 2; ++it) {
      int li = tid + it * 256;       // 0..511
      int row = li >> 2, kq = li & 3;
      {
        int gr = (EPI == 2) ? rmap_s[row] : min(mBase + row, Mr - 1);
        uint4 v = *(const uint4*)(A + (size_t)gr * K + kt * BK + kq * 8);
        *(uint4*)&As[row * LDT + kq * 8] = v;
      }
      {
        int gr = min(nBase + row, Nr - 1);
        uint4 v = *(const uint4*)(Bm + (size_t)gr * K + kt * BK + kq * 8);
        *(uint4*)&Bs[row * LDT + kq * 8] = v;
      }
    }
    __syncthreads();
    bf16x8 af[4], bfr[4];
    for (int i = 0; i < 4; ++i)
      af[i] = *(const bf16x8*)&As[(wm + i * 16 + lm) * LDT + lq * 8];
    for (int j = 0; j < 4; ++j)
      bfr[j] = *(const bf16x8*)&Bs[(wn + j * 16 + lm) * LDT + lq * 8];
    for (int i = 0; i < 4; ++i)
      for (int j = 0; j < 4; ++j)
        acc[i][j] = __builtin_amdgcn_mfma_f32_16x16x32_bf16(af[i], bfr[j], acc[i][j], 0, 0, 0);
    __syncthreads();
  }

  // epilogue: C row = (lane>>4)*4 + reg, col = lane&15
  for (int i = 0; i < 4; ++i) {
    int rloc0 = wm + i * 16 + (lane >> 4) * 4;
    for (int j = 0; j < 4; ++j) {
      int col = nBase + wn + j * 16 + (lane & 15);
      for (int r = 0; r < 4; ++r) {
        int rloc = rloc0 + r;
        float v = acc[i][j][r];
        if (EPI == 0) {
          int row = mBase + rloc;
          if (row < Mr && col < Nr)
            ((float*)outv)[(size_t)row * Nr + col] = v + bias0[col] + bias1[col];
        } else if (EPI == 1) {
          int row = mBase + rloc;
          if (row < Mr && col < Nr) {
            if (col < 512) ((u16*)outv)[(size_t)row * 512 + col] = f2bf(v + bias0[col]);
            else           out1[(size_t)row * 512 + (col - 512)] = v + bias1[col - 512];
          }
        } else {
          if (col < Nr && mBase + rloc < nact)
            ((float*)outv)[(size_t)rmap_s[rloc] * Nr + col] = v + bias0[col];
        }
      }
    }
  }
}

// ---------------- persistent LSTM: all 50 steps in one launch ----------------
// 64 blocks x 256 threads. Block j owns units u0=j*8..j*8+7 (32 gate columns).
// Cross-block exchange (h, flags) goes through the MALL coherence point via
// RELAXED agent-scope atomics (cache-bypassing) — NO fences, NO L2
// writeback/invalidate. h packed 2xbf16 per u32 word, ping-pong hx[2][64][256].
// Safety: entering step t requires all flags >= t, which implies every block
// finished reading buffer (t-1)&1 before anyone overwrites it at step t+1.
__global__ __launch_bounds__(256, 1) void lstm_seq(const float* __restrict__ w_hh,
                                                   const float* __restrict__ xW,
                                                   const float* __restrict__ cbuf,
                                                   u32* __restrict__ hx,
                                                   u16* __restrict__ Hs,
                                                   int* __restrict__ flags) {
  __shared__ u16 wsm[32 * 520];
  __shared__ float gsm[64][36];
  int tid = threadIdx.x;
  int j = blockIdx.x;
  int u0 = j * 8;

  // stage w_hh chunk (rows g*512+u0+ul for g=0..3, ul=0..7) -> wsm[g*8+ul][0..511]
  {
    int r = tid >> 3;              // 0..31
    int cc = (tid & 7) * 64;       // 64 floats per thread
    const float* src = w_hh + (size_t)((r >> 3) * HID + u0 + (r & 7)) * HID + cc;
    u16* dst = &wsm[r * 520 + cc];
#pragma unroll
    for (int q = 0; q < 16; ++q) {
      float4 v = ((const float4*)src)[q];
      ushort4 o; o.x = f2bf(v.x); o.y = f2bf(v.y); o.z = f2bf(v.z); o.w = f2bf(v.w);
      ((ushort4*)dst)[q] = o;
    }
  }
  __syncthreads();

  int wave = tid >> 6, lane = tid & 63;
  int lm = lane & 15, lq = lane >> 4;

  // time-invariant B fragments (compiler may cache in regs or re-read LDS)
  bf16x8 bfrag[2][16];
#pragma unroll
  for (int n = 0; n < 2; ++n)
#pragma unroll
    for (int kq = 0; kq < 16; ++kq)
      bfrag[n][kq] = *(const bf16x8*)&wsm[(n * 16 + lm) * 520 + kq * 32 + lq * 8];

  // pointwise mapping: thread owns (b = tid>>2, unit pair up = tid&3) -> units u0+2up, u0+2up+1
  int b = tid >> 2, up = tid & 3;
  float creg[2];
  {
    float2 c2 = *(const float2*)&cbuf[(size_t)b * HID + u0 + 2 * up];
    creg[0] = c2.x; creg[1] = c2.y;
  }

  const int arow32 = (wave * 16 + lm) * 256;   // dword row base for A-fragments

  for (int t = 0; t < TT; ++t) {
    const u32* hcur = hx + (size_t)(t & 1) * (NB * 256);
    u32* hnxt = (u32*)(hx + (size_t)((t + 1) & 1) * (NB * 256));

    // prefetch xW gate terms (independent of h; overlaps the poll)
    float xg[4][2];
    {
      const float* xwp = xW + (size_t)(b * TT + t) * G4 + u0 + 2 * up;
#pragma unroll
      for (int g = 0; g < 4; ++g) {
        float2 v = *(const float2*)&xwp[g * HID];
        xg[g][0] = v.x; xg[g][1] = v.y;
      }
    }

    // wait for h(t) to be complete at MALL (relaxed polls: no cache inval)
    if (t > 0) {
      if (tid < 64) {
        while (__hip_atomic_load(&flags[tid], __ATOMIC_RELAXED, __HIP_MEMORY_SCOPE_AGENT) < t)
          __builtin_amdgcn_s_sleep(2);
      }
      __syncthreads();
    }

    // A fragments: relaxed agent atomic dword loads (bypass L2 -> MALL-current)
    bf16x8 afr[16];
#pragma unroll
    for (int kq = 0; kq < 16; ++kq) {
      union { u32 u[4]; bf16x8 v; } tmp;
      const u32* p = hcur + arow32 + kq * 16 + lq * 4;
#pragma unroll
      for (int w = 0; w < 4; ++w)
        tmp.u[w] = __hip_atomic_load(p + w, __ATOMIC_RELAXED, __HIP_MEMORY_SCOPE_AGENT);
      afr[kq] = tmp.v;
    }

    f32x4 acc0 = (f32x4){0.f, 0.f, 0.f, 0.f};
    f32x4 acc1 = (f32x4){0.f, 0.f, 0.f, 0.f};
#pragma unroll
    for (int kq = 0; kq < 16; ++kq) {
      acc0 = __builtin_amdgcn_mfma_f32_16x16x32_bf16(afr[kq], bfrag[0][kq], acc0, 0, 0, 0);
      acc1 = __builtin_amdgcn_mfma_f32_16x16x32_bf16(afr[kq], bfrag[1][kq], acc1, 0, 0, 0);
    }
#pragma unroll
    for (int r = 0; r < 4; ++r) {
      gsm[wave * 16 + lq * 4 + r][lm]      = acc0[r];
      gsm[wave * 16 + lq * 4 + r][16 + lm] = acc1[r];
    }
    __syncthreads();

    // pointwise: 2 adjacent units per thread -> pack one dword
    float hn2[2];
#pragma unroll
    for (int e = 0; e < 2; ++e) {
      int ul = 2 * up + e;
      float gi = gsm[b][ul]      + xg[0][e];
      float gf = gsm[b][8 + ul]  + xg[1][e];
      float gg = gsm[b][16 + ul] + xg[2][e];
      float go = gsm[b][24 + ul] + xg[3][e];
      float si = 1.f / (1.f + __expf(-gi));
      float sf = 1.f / (1.f + __expf(-gf));
      float so = 1.f / (1.f + __expf(-go));
      float tg = tanhf(gg);
      float cn = sf * creg[e] + si * tg;
      creg[e] = cn;
      hn2[e] = so * tanhf(cn);
    }
    u32 hw = (u32)f2bf(hn2[0]) | ((u32)f2bf(hn2[1]) << 16);
    __hip_atomic_store(&hnxt[b * 256 + (u0 >> 1) + up], hw,
                       __ATOMIC_RELAXED, __HIP_MEMORY_SCOPE_AGENT);
    ((u32*)Hs)[((size_t)(b * TT + t) * HID + u0) / 2 + up] = hw;   // for FC (post-kernel)

    // barrier drains vmcnt (compiler emits s_waitcnt vmcnt(0) before s_barrier),
    // so all 256 threads' h-stores are at MALL before the flag bump.
    __syncthreads();
    if (tid == 0)
      __hip_atomic_store(&flags[j], t + 1, __ATOMIC_RELAXED, __HIP_MEMORY_SCOPE_AGENT);
  }
}

// ---------------- launcher ----------------
extern "C" void kernel_launch(void* const* d_in, const int* in_sizes, int n_in,
                              void* d_out, int out_size, void* d_ws, size_t ws_size,
                              hipStream_t stream) {
  const float* encoder_out = (const float*)d_in[0];
  const int*   caps        = (const int*)d_in[1];
  const int*   cap_len     = (const int*)d_in[2];
  const float* emb         = (const float*)d_in[3];
  const float* w_ih        = (const float*)d_in[4];
  const float* b_ih        = (const float*)d_in[5];
  const float* w_hh        = (const float*)d_in[6];
  const float* b_hh        = (const float*)d_in[7];
  const float* w_init_h    = (const float*)d_in[8];
  const float* b_init_h    = (const float*)d_in[9];
  const float* w_init_c    = (const float*)d_in[10];
  const float* b_init_c    = (const float*)d_in[11];
  const float* w_fc        = (const float*)d_in[12];
  const float* b_fc        = (const float*)d_in[13];
  float* out = (float*)d_out;

  char* ws = (char*)d_ws;
  int*   sind   = (int*)(ws + 0);          // 256 B
  int*   dlen   = (int*)(ws + 256);        // 256 B
  int*   nact   = (int*)(ws + 512);        // 64 B
  int*   flags  = (int*)(ws + 576);        // 256 B
  int*   rowmap = (int*)(ws + 832);        // 12800 B
  int*   zmap   = (int*)(ws + 13632);      // 12800 B
  float* cbuf   = (float*)(ws + 26496);    // 64*512*4 = 131072
  u16*   hbuf   = (u16*)(ws + 157568);     // 2*64*512*2 = 131072 (hx ping-pong)
  float* xW     = (float*)(ws + 288640);   // 3200*2048*4 = 26214400
  u16*   Hs     = (u16*)(ws + 26503040);   // 3200*512*2 = 3276800
  u16*   Xb     = (u16*)(ws + 29779840);   // 3276800
  u16*   Wih    = (u16*)(ws + 33056640);   // 2097152
  u16*   Winit  = (u16*)(ws + 35153792);   // 4194304
  u16*   Wfc    = (u16*)(ws + 39348096);   // 30720000
  u16*   Ebf    = (u16*)(ws + 70068096);   // 262144  -> end 70330240

  sort_k<<<1, 256, 0, stream>>>(cap_len, caps, out, sind, dlen, rowmap, zmap, nact, flags);
  conv4<<<1024, 256, 0, stream>>>(w_ih, Wih, 262144);
  conv_winit_k<<<2048, 256, 0, stream>>>(w_init_h, w_init_c, Winit);
  conv4<<<15000, 256, 0, stream>>>(w_fc, Wfc, 3840000);
  gather_enc_k<<<128, 256, 0, stream>>>(encoder_out, sind, Ebf);
  gather_x_k<<<1600, 256, 0, stream>>>(emb, caps, sind, Xb);

  // h0 (bf16, into hx buffer 0) | c0 (fp32)
  gemm_bt<1><<<dim3(1, 8), 256, 0, stream>>>(Ebf, Winit, 64, 1024, 2048,
                                             hbuf, cbuf, b_init_h, b_init_c,
                                             nullptr, nullptr, nullptr);
  // xW = X @ w_ih^T + b_ih + b_hh  (all steps at once)
  gemm_bt<0><<<dim3(25, 16), 256, 0, stream>>>(Xb, Wih, 3200, 2048, 512,
                                               xW, nullptr, b_ih, b_hh,
                                               nullptr, nullptr, nullptr);
  // all 50 LSTM steps, one launch, MALL-atomic sync
  lstm_seq<<<64, 256, 0, stream>>>(w_hh, xW, cbuf, (u32*)hbuf, Hs, flags);
  // predictions = Hs @ w_fc^T + b_fc (compacted rows; masked rows zero-filled)
  gemm_bt<2><<<dim3(25, 235), 256, 0, stream>>>(Hs, Wfc, 3200, VOC, 512,
                                                out, nullptr, b_fc, nullptr,
                                                rowmap, zmap, nact);
}

// Round 4
// 948.448 us; speedup vs baseline: 1.6542x; 1.2540x over previous
//
#include <hip/hip_runtime.h>

// Problem constants
#define NB    64      // batch
#define LCAP  51      // caption length
#define TT    50      // decode steps
#define HID   512
#define EMB   512
#define VOC   30000
#define ENCD  2048
#define G4    2048    // 4*HID

typedef unsigned short u16;
typedef unsigned int   u32;
typedef __attribute__((ext_vector_type(8))) short bf16x8;
typedef __attribute__((ext_vector_type(4))) float f32x4;
typedef __attribute__((ext_vector_type(4))) unsigned int u32x4;

__device__ __forceinline__ u16 f2bf(float x) {
  union { float f; unsigned u; } v; v.f = x;
  unsigned r = v.u + 0x7fffu + ((v.u >> 16) & 1u);
  return (u16)(r >> 16);
}

__device__ __forceinline__ float fast_sigmoid(float x) {
  return 1.f / (1.f + __expf(-x));
}
__device__ __forceinline__ float fast_tanh(float x) {
  float xx = fminf(fmaxf(x, -10.f), 10.f);
  float e = __expf(2.f * xx);
  return (e - 1.f) * __frcp_rn(e + 1.f);
}

// ---------------- sort + int outputs + row compaction + sync-counter init ----------------
__global__ __launch_bounds__(256) void sort_k(const int* __restrict__ cap_len,
                                              const int* __restrict__ caps,
                                              float* __restrict__ out,
                                              int* __restrict__ sind,
                                              int* __restrict__ dlen,
                                              int* __restrict__ rowmap,
                                              int* __restrict__ zmap,
                                              int* __restrict__ nact,
                                              int* __restrict__ flags) {
  __shared__ int smlen[NB];
  __shared__ int smpos[NB];
  __shared__ int sdl[NB];
  __shared__ int off[NB];
  __shared__ int zoff[NB];
  int tid = threadIdx.x;
  if (tid < NB) { smlen[tid] = cap_len[tid]; flags[tid] = 0; }
  __syncthreads();
  if (tid < NB) {
    int li = smlen[tid];
    int rank = 0;
    for (int j = 0; j < NB; ++j) {
      int lj = smlen[j];
      rank += (lj > li || (lj == li && j < tid)) ? 1 : 0;
    }
    smpos[rank] = tid;
  }
  __syncthreads();
  if (tid < NB) {
    int src = smpos[tid];
    int dl = smlen[src] - 1;
    sind[tid] = src;
    dlen[tid] = dl;
    sdl[tid] = dl;
    float* caps_out = out + (size_t)NB * TT * VOC;          // 96,000,000
    for (int l = 0; l < LCAP; ++l)
      caps_out[tid * LCAP + l] = (float)caps[src * LCAP + l];
    out[96003264 + tid] = (float)dl;       // dec_len
    out[96003328 + tid] = (float)src;      // sort_ind
  }
  __syncthreads();
  if (tid == 0) {
    int s = 0, z = 0;
    for (int b = 0; b < NB; ++b) {
      off[b] = s;  s += sdl[b];
      zoff[b] = z; z += TT - sdl[b];
    }
    *nact = s;
  }
  __syncthreads();
  for (int m = tid; m < NB * TT; m += 256) {
    int b = (m * 5243) >> 18;     // m/50 for m<43690
    int t = m - b * TT;
    if (t < sdl[b]) rowmap[off[b] + t] = m;
    else            zmap[zoff[b] + (t - sdl[b])] = m;
  }
}

// ---------------- converts / gathers ----------------
__global__ __launch_bounds__(256) void conv4(const float* __restrict__ src,
                                             u16* __restrict__ dst, int n4) {
  int i = blockIdx.x * 256 + threadIdx.x;
  if (i >= n4) return;
  float4 v = ((const float4*)src)[i];
  ushort4 o;
  o.x = f2bf(v.x); o.y = f2bf(v.y); o.z = f2bf(v.z); o.w = f2bf(v.w);
  ((ushort4*)dst)[i] = o;
}

// Winit = concat(w_init_h, w_init_c) rows -> [1024][2048] bf16
__global__ __launch_bounds__(256) void conv_winit_k(const float* __restrict__ wh,
                                                    const float* __restrict__ wc,
                                                    u16* __restrict__ dst) {
  int i = blockIdx.x * 256 + threadIdx.x;   // i over 2097152/4
  if (i >= 524288) return;
  int e = i * 4;
  int row = e >> 11;           // /2048
  int col = e & 2047;
  const float* src = (row < 512) ? (wh + (size_t)row * 2048 + col)
                                 : (wc + (size_t)(row - 512) * 2048 + col);
  float4 v = *(const float4*)src;
  ushort4 o;
  o.x = f2bf(v.x); o.y = f2bf(v.y); o.z = f2bf(v.z); o.w = f2bf(v.w);
  ((ushort4*)dst)[i] = o;
}

// enc_bf[r][k] = bf16(encoder_out[sind[r]][k])
__global__ __launch_bounds__(256) void gather_enc_k(const float* __restrict__ enc,
                                                    const int* __restrict__ sind,
                                                    u16* __restrict__ dst) {
  int i = blockIdx.x * 256 + threadIdx.x;   // over 64*2048/4
  if (i >= 32768) return;
  int e = i * 4;
  int r = e >> 11;
  int k = e & 2047;
  float4 v = *(const float4*)(enc + (size_t)sind[r] * ENCD + k);
  ushort4 o;
  o.x = f2bf(v.x); o.y = f2bf(v.y); o.z = f2bf(v.z); o.w = f2bf(v.w);
  ((ushort4*)dst)[i] = o;
}

// Xb[(b*50+t)][k] = bf16(emb[caps[sind[b]*51 + t]][k])
__global__ __launch_bounds__(256) void gather_x_k(const float* __restrict__ emb,
                                                  const int* __restrict__ caps,
                                                  const int* __restrict__ sind,
                                                  u16* __restrict__ dst) {
  int i = blockIdx.x * 256 + threadIdx.x;   // over 3200*512/4
  if (i >= 409600) return;
  int e = i * 4;
  int m = e >> 9;              // /512
  int k = e & 511;
  unsigned b = ((unsigned)m * 5243u) >> 18;   // m/50
  int t = m - (int)b * TT;
  int cap = caps[sind[b] * LCAP + t];
  float4 v = *(const float4*)(emb + (size_t)cap * EMB + k);
  ushort4 o;
  o.x = f2bf(v.x); o.y = f2bf(v.y); o.z = f2bf(v.z); o.w = f2bf(v.w);
  ((ushort4*)dst)[i] = o;
}

// ---------------- bf16 MFMA GEMM: C[M][N] = A[M][K] * B[N][K]^T ----------------
// grid: x = m-blocks (consecutive blocks share a weight panel), y = n-blocks.
// EPI 0: xW   -> out[row*Nr+col] = acc + bias0[col] + bias1[col]
// EPI 1: init -> col<512: h0 bf16 into outv; else c0 fp32 into out1
// EPI 2: fc   -> compacted rows via rowmap; masked rows zero-filled in slices
#define BM 128
#define BN 128
#define BK 32
#define LDT 40    // LDS row stride (bf16 elems); 2-way max bank aliasing

template <int EPI>
__global__ __launch_bounds__(256) void gemm_bt(const u16* __restrict__ A,
                                               const u16* __restrict__ Bm,
                                               int Mr, int Nr, int K,
                                               void* __restrict__ outv,
                                               float* __restrict__ out1,
                                               const float* __restrict__ bias0,
                                               const float* __restrict__ bias1,
                                               const int* __restrict__ rowmap,
                                               const int* __restrict__ zmap,
                                               const int* __restrict__ nactp) {
  __shared__ u16 As[BM * LDT];
  __shared__ u16 Bs[BN * LDT];
  __shared__ int rmap_s[BM];
  int tid = threadIdx.x;
  int mBase = blockIdx.x * BM;
  int nBase = blockIdx.y * BN;
  int nact = Mr;

  if (EPI == 2) {
    nact = nactp[0];
    int nz = Mr - nact;
    // zero-fill duty: every block zeroes its column slice for rows r = x (mod gridDim.x)
    if (tid < 32 && nz > 0) {
      int nc4 = min(BN, Nr - nBase) >> 2;   // float4 per slice (<=32)
      float4 zz = {0.f, 0.f, 0.f, 0.f};
      if (tid < nc4) {
        for (int r = blockIdx.x; r < nz; r += gridDim.x) {
          float4* dst = (float4*)((float*)outv + (size_t)zmap[r] * Nr + nBase);
          dst[tid] = zz;
        }
      }
    }
    int na = (nact + BM - 1) >> 7;          // active m-blocks
    if ((int)blockIdx.x >= na) return;
    if (tid < BM) {
      int idx = mBase + tid;
      rmap_s[tid] = (idx < nact) ? rowmap[idx] : rowmap[nact - 1];
    }
    __syncthreads();
  }

  int wid = tid >> 6, lane = tid & 63;
  int wm = (wid >> 1) * 64, wn = (wid & 1) * 64;
  int lm = lane & 15, lq = lane >> 4;

  f32x4 acc[4][4];
  for (int i = 0; i < 4; ++i)
    for (int j = 0; j < 4; ++j)
      acc[i][j] = (f32x4){0.f, 0.f, 0.f, 0.f};

  int nkt = K / BK;
  for (int kt = 0; kt < nkt; ++kt) {
    for (int it = 0; it < 2; ++it) {
      int li = tid + it * 256;       // 0..511
      int row = li >> 2, kq = li & 3;
      {
        int gr = (EPI == 2) ? rmap_s[row] : min(mBase + row, Mr - 1);
        uint4 v = *(const uint4*)(A + (size_t)gr * K + kt * BK + kq * 8);
        *(uint4*)&As[row * LDT + kq * 8] = v;
      }
      {
        int gr = min(nBase + row, Nr - 1);
        uint4 v = *(const uint4*)(Bm + (size_t)gr * K + kt * BK + kq * 8);
        *(uint4*)&Bs[row * LDT + kq * 8] = v;
      }
    }
    __syncthreads();
    bf16x8 af[4], bfr[4];
    for (int i = 0; i < 4; ++i)
      af[i] = *(const bf16x8*)&As[(wm + i * 16 + lm) * LDT + lq * 8];
    for (int j = 0; j < 4; ++j)
      bfr[j] = *(const bf16x8*)&Bs[(wn + j * 16 + lm) * LDT + lq * 8];
    for (int i = 0; i < 4; ++i)
      for (int j = 0; j < 4; ++j)
        acc[i][j] = __builtin_amdgcn_mfma_f32_16x16x32_bf16(af[i], bfr[j], acc[i][j], 0, 0, 0);
    __syncthreads();
  }

  // epilogue: C row = (lane>>4)*4 + reg, col = lane&15
  for (int i = 0; i < 4; ++i) {
    int rloc0 = wm + i * 16 + (lane >> 4) * 4;
    for (int j = 0; j < 4; ++j) {
      int col = nBase + wn + j * 16 + (lane & 15);
      for (int r = 0; r < 4; ++r) {
        int rloc = rloc0 + r;
        float v = acc[i][j][r];
        if (EPI == 0) {
          int row = mBase + rloc;
          if (row < Mr && col < Nr)
            ((float*)outv)[(size_t)row * Nr + col] = v + bias0[col] + bias1[col];
        } else if (EPI == 1) {
          int row = mBase + rloc;
          if (row < Mr && col < Nr) {
            if (col < 512) ((u16*)outv)[(size_t)row * 512 + col] = f2bf(v + bias0[col]);
            else           out1[(size_t)row * 512 + (col - 512)] = v + bias1[col - 512];
          }
        } else {
          if (col < Nr && mBase + rloc < nact)
            ((float*)outv)[(size_t)rmap_s[rloc] * Nr + col] = v + bias0[col];
        }
      }
    }
  }
}

// ---------------- persistent LSTM: all 50 steps in one launch ----------------
// 64 blocks x 256 threads, 1 block/CU. Block j owns units u0=j*8..j*8+7
// (32 gate columns), w_hh bf16 B-fragments in registers across all steps.
// Cross-block exchange through the MALL coherence point:
//   - h broadcast: WIDE cache-bypass accesses (global_load/store_dwordx4
//     sc0 sc1 via inline asm) — full 64B-line utilization, no L2 inval.
//   - sync: ONE monotonic counter, relaxed agent atomicAdd + single-lane
//     poll. Same-address atomics are self-ordered; no fences anywhere.
// Wave 0 performs the packed h-store and flag bump privately (its own
// s_waitcnt vmcnt(0) drains the stores) — no extra block barrier.
// Ping-pong safety: entering step t requires cnt >= 64*t, which implies every
// block finished READING buffer (t-1)&1, so overwriting it at t is safe.
__global__ __launch_bounds__(256, 1) void lstm_seq(const float* __restrict__ w_hh,
                                                   const float* __restrict__ xW,
                                                   const float* __restrict__ cbuf,
                                                   u32* __restrict__ hx,
                                                   u32* __restrict__ Hs32,
                                                   int* __restrict__ cnt) {
  __shared__ u16 wsm[32 * 520];
  __shared__ float gsm[64][36];
  __shared__ u32 hsh[256];
  int tid = threadIdx.x;
  int j = blockIdx.x;
  int u0 = j * 8;

  // stage w_hh chunk (rows g*512+u0+ul for g=0..3, ul=0..7) -> wsm[g*8+ul][0..511]
  {
    int r = tid >> 3;              // 0..31
    int cc = (tid & 7) * 64;       // 64 floats per thread
    const float* src = w_hh + (size_t)((r >> 3) * HID + u0 + (r & 7)) * HID + cc;
    u16* dst = &wsm[r * 520 + cc];
#pragma unroll
    for (int q = 0; q < 16; ++q) {
      float4 v = ((const float4*)src)[q];
      ushort4 o; o.x = f2bf(v.x); o.y = f2bf(v.y); o.z = f2bf(v.z); o.w = f2bf(v.w);
      ((ushort4*)dst)[q] = o;
    }
  }
  __syncthreads();

  int wave = tid >> 6, lane = tid & 63;
  int lm = lane & 15, lq = lane >> 4;

  // time-invariant B fragments
  bf16x8 bfrag[2][16];
#pragma unroll
  for (int n = 0; n < 2; ++n)
#pragma unroll
    for (int kq = 0; kq < 16; ++kq)
      bfrag[n][kq] = *(const bf16x8*)&wsm[(n * 16 + lm) * 520 + kq * 32 + lq * 8];

  // pointwise mapping: thread owns (b = tid>>2, unit pair up = tid&3)
  int b = tid >> 2, up = tid & 3;
  float creg[2];
  {
    float2 c2 = *(const float2*)&cbuf[(size_t)b * HID + u0 + 2 * up];
    creg[0] = c2.x; creg[1] = c2.y;
  }

  const int arow32 = (wave * 16 + lm) * 256;   // dword row base for A-fragments

  for (int t = 0; t < TT; ++t) {
    const u32* hcur = hx + (size_t)(t & 1) * (NB * 256);
    u32* hnxt = hx + (size_t)((t + 1) & 1) * (NB * 256);

    // prefetch xW gate terms (independent of h; overlaps the poll)
    float xg[4][2];
    {
      const float* xwp = xW + (size_t)(b * TT + t) * G4 + u0 + 2 * up;
#pragma unroll
      for (int g = 0; g < 4; ++g) {
        float2 v = *(const float2*)&xwp[g * HID];
        xg[g][0] = v.x; xg[g][1] = v.y;
      }
    }

    // wait for h(t) complete at MALL: single-lane poll on monotonic counter
    if (t > 0 && tid == 0) {
      while (__hip_atomic_load(cnt, __ATOMIC_RELAXED, __HIP_MEMORY_SCOPE_AGENT) < 64 * t)
        __builtin_amdgcn_s_sleep(1);
    }
    __syncthreads();

    // A fragments: wide cache-bypass loads straight from MALL
    u32x4 raw[16];
#pragma unroll
    for (int kq = 0; kq < 16; ++kq) {
      const u32* p = hcur + arow32 + kq * 16 + lq * 4;
      asm volatile("global_load_dwordx4 %0, %1, off sc0 sc1"
                   : "=v"(raw[kq]) : "v"(p) : "memory");
    }
    asm volatile("s_waitcnt vmcnt(0)"
                 : "+v"(raw[0]), "+v"(raw[1]), "+v"(raw[2]), "+v"(raw[3]),
                   "+v"(raw[4]), "+v"(raw[5]), "+v"(raw[6]), "+v"(raw[7]),
                   "+v"(raw[8]), "+v"(raw[9]), "+v"(raw[10]), "+v"(raw[11]),
                   "+v"(raw[12]), "+v"(raw[13]), "+v"(raw[14]), "+v"(raw[15])
                 :: "memory");

    f32x4 acc0 = (f32x4){0.f, 0.f, 0.f, 0.f};
    f32x4 acc1 = (f32x4){0.f, 0.f, 0.f, 0.f};
#pragma unroll
    for (int kq = 0; kq < 16; ++kq) {
      bf16x8 a = __builtin_bit_cast(bf16x8, raw[kq]);
      acc0 = __builtin_amdgcn_mfma_f32_16x16x32_bf16(a, bfrag[0][kq], acc0, 0, 0, 0);
      acc1 = __builtin_amdgcn_mfma_f32_16x16x32_bf16(a, bfrag[1][kq], acc1, 0, 0, 0);
    }
#pragma unroll
    for (int r = 0; r < 4; ++r) {
      gsm[wave * 16 + lq * 4 + r][lm]      = acc0[r];
      gsm[wave * 16 + lq * 4 + r][16 + lm] = acc1[r];
    }
    __syncthreads();

    // pointwise: 2 adjacent units per thread -> pack one dword into LDS
    float hn2[2];
#pragma unroll
    for (int e = 0; e < 2; ++e) {
      int ul = 2 * up + e;
      float gi = gsm[b][ul]      + xg[0][e];
      float gf = gsm[b][8 + ul]  + xg[1][e];
      float gg = gsm[b][16 + ul] + xg[2][e];
      float go = gsm[b][24 + ul] + xg[3][e];
      float cn = fast_sigmoid(gf) * creg[e] + fast_sigmoid(gi) * fast_tanh(gg);
      creg[e] = cn;
      hn2[e] = fast_sigmoid(go) * fast_tanh(cn);
    }
    hsh[b * 4 + up] = (u32)f2bf(hn2[0]) | ((u32)f2bf(hn2[1]) << 16);
    __syncthreads();

    // wave 0: one 16B bypass store per batch + Hs store + private drain + flag
    if (tid < 64) {
      u32x4 hv = *(const u32x4*)&hsh[tid * 4];
      u32* dst = hnxt + tid * 256 + j * 4;
      asm volatile("global_store_dwordx4 %0, %1, off sc0 sc1"
                   :: "v"(dst), "v"(hv) : "memory");
      *(u32x4*)(Hs32 + ((size_t)tid * TT + t) * 256 + j * 4) = hv;
      asm volatile("s_waitcnt vmcnt(0)" ::: "memory");
      if (tid == 0)
        __hip_atomic_fetch_add(cnt, 1, __ATOMIC_RELAXED, __HIP_MEMORY_SCOPE_AGENT);
    }
  }
}

// ---------------- launcher ----------------
extern "C" void kernel_launch(void* const* d_in, const int* in_sizes, int n_in,
                              void* d_out, int out_size, void* d_ws, size_t ws_size,
                              hipStream_t stream) {
  const float* encoder_out = (const float*)d_in[0];
  const int*   caps        = (const int*)d_in[1];
  const int*   cap_len     = (const int*)d_in[2];
  const float* emb         = (const float*)d_in[3];
  const float* w_ih        = (const float*)d_in[4];
  const float* b_ih        = (const float*)d_in[5];
  const float* w_hh        = (const float*)d_in[6];
  const float* b_hh        = (const float*)d_in[7];
  const float* w_init_h    = (const float*)d_in[8];
  const float* b_init_h    = (const float*)d_in[9];
  const float* w_init_c    = (const float*)d_in[10];
  const float* b_init_c    = (const float*)d_in[11];
  const float* w_fc        = (const float*)d_in[12];
  const float* b_fc        = (const float*)d_in[13];
  float* out = (float*)d_out;

  char* ws = (char*)d_ws;
  int*   sind   = (int*)(ws + 0);          // 256 B
  int*   dlen   = (int*)(ws + 256);        // 256 B
  int*   nact   = (int*)(ws + 512);        // 64 B
  int*   flags  = (int*)(ws + 576);        // 256 B (flags[0] = sync counter)
  int*   rowmap = (int*)(ws + 832);        // 12800 B
  int*   zmap   = (int*)(ws + 13632);      // 12800 B
  float* cbuf   = (float*)(ws + 26496);    // 64*512*4 = 131072
  u16*   hbuf   = (u16*)(ws + 157568);     // 2*64*512*2 = 131072 (hx ping-pong)
  float* xW     = (float*)(ws + 288640);   // 3200*2048*4 = 26214400
  u16*   Hs     = (u16*)(ws + 26503040);   // 3200*512*2 = 3276800
  u16*   Xb     = (u16*)(ws + 29779840);   // 3276800
  u16*   Wih    = (u16*)(ws + 33056640);   // 2097152
  u16*   Winit  = (u16*)(ws + 35153792);   // 4194304
  u16*   Wfc    = (u16*)(ws + 39348096);   // 30720000
  u16*   Ebf    = (u16*)(ws + 70068096);   // 262144  -> end 70330240

  sort_k<<<1, 256, 0, stream>>>(cap_len, caps, out, sind, dlen, rowmap, zmap, nact, flags);
  conv4<<<1024, 256, 0, stream>>>(w_ih, Wih, 262144);
  conv_winit_k<<<2048, 256, 0, stream>>>(w_init_h, w_init_c, Winit);
  conv4<<<15000, 256, 0, stream>>>(w_fc, Wfc, 3840000);
  gather_enc_k<<<128, 256, 0, stream>>>(encoder_out, sind, Ebf);
  gather_x_k<<<1600, 256, 0, stream>>>(emb, caps, sind, Xb);

  // h0 (bf16, into hx buffer 0) | c0 (fp32)
  gemm_bt<1><<<dim3(1, 8), 256, 0, stream>>>(Ebf, Winit, 64, 1024, 2048,
                                             hbuf, cbuf, b_init_h, b_init_c,
                                             nullptr, nullptr, nullptr);
  // xW = X @ w_ih^T + b_ih + b_hh  (all steps at once)
  gemm_bt<0><<<dim3(25, 16), 256, 0, stream>>>(Xb, Wih, 3200, 2048, 512,
                                               xW, nullptr, b_ih, b_hh,
                                               nullptr, nullptr, nullptr);
  // all 50 LSTM steps, one launch, MALL-atomic sync
  lstm_seq<<<64, 256, 0, stream>>>(w_hh, xW, cbuf, (u32*)hbuf, (u32*)Hs, flags);
  // predictions = Hs @ w_fc^T + b_fc (compacted rows; masked rows zero-filled)
  gemm_bt<2><<<dim3(25, 235), 256, 0, stream>>>(Hs, Wfc, 3200, VOC, 512,
                                                out, nullptr, b_fc, nullptr,
                                                rowmap, zmap, nact);
}